// Round 12
// baseline (209.848 us; speedup 1.0000x reference)
//
#include <hip/hip_runtime.h>

#define DIM 128
#define BINSHIFT 7
#define BINSZ 128          // nodes per bin
#define BCAP 2560          // edges capacity per bin: Poisson(2048)+11sigma
#define EPB 8192           // edges per binning block

typedef __attribute__((ext_vector_type(8))) short bf16x8;
typedef __attribute__((ext_vector_type(4))) float f32x4;

__device__ inline unsigned short f2b(float f) {
    unsigned u = __builtin_bit_cast(unsigned, f);
    unsigned r = (u + 0x7FFFu + ((u >> 16) & 1u)) >> 16;
    return (unsigned short)r;
}
__device__ inline float b2f(unsigned short h) {
    unsigned u = ((unsigned)h) << 16;
    return __builtin_bit_cast(float, u);
}

// ---------------------------------------------------------------- prep: [0,ebB) bin edges | [ebB,ebB+castB) cast x | last 4: W1 -> bf16 W^T
__global__ __launch_bounds__(1024)
void prep(const int* __restrict__ src, const int* __restrict__ dst,
          unsigned* __restrict__ gcur, unsigned* __restrict__ binned, int E, int nbins,
          const float* __restrict__ x, unsigned short* __restrict__ xb, int n8,
          const float* __restrict__ W1, unsigned short* __restrict__ wT1,
          int ebB, int castB)
{
    const int t = threadIdx.x;
    const int bid = blockIdx.x;
    if (bid < ebB) {
        __shared__ unsigned hist[1024];
        __shared__ unsigned base[1024];
        const long long bb = (long long)bid * EPB;
        if (t < nbins) hist[t] = 0;
        __syncthreads();
        unsigned pk[8], pos[8];
        int bn[8];
        bool ok[8];
        #pragma unroll
        for (int i = 0; i < 8; ++i) {
            long long idx = bb + i * 1024 + t;
            ok[i] = idx < E;
            if (ok[i]) {
                int s = src[idx], d = dst[idx];
                pk[i] = ((unsigned)(d & (BINSZ - 1)) << 17) | (unsigned)s;
                bn[i] = d >> BINSHIFT;
                pos[i] = atomicAdd(&hist[bn[i]], 1u);
            }
        }
        __syncthreads();
        if (t < nbins) base[t] = (unsigned)t * BCAP + atomicAdd(&gcur[t], hist[t]);
        __syncthreads();
        #pragma unroll
        for (int i = 0; i < 8; ++i) {
            if (ok[i]) {
                unsigned off = base[bn[i]] + pos[i];
                if (off < (unsigned)(bn[i] + 1) * BCAP) binned[off] = pk[i];
            }
        }
    } else if (bid < ebB + castB) {
        int i = (bid - ebB) * 1024 + t;
        if (i >= n8) return;
        float4 a = ((const float4*)x)[i * 2];
        float4 b = ((const float4*)x)[i * 2 + 1];
        bf16x8 o;
        o[0] = (short)f2b(a.x); o[1] = (short)f2b(a.y); o[2] = (short)f2b(a.z); o[3] = (short)f2b(a.w);
        o[4] = (short)f2b(b.x); o[5] = (short)f2b(b.y); o[6] = (short)f2b(b.z); o[7] = (short)f2b(b.w);
        ((bf16x8*)xb)[i] = o;
    } else {
        int r = bid - ebB - castB;                 // 0..3
        int idx = r * 1024 + t;                    // 0..4095
        int n = idx >> 5, k = (idx & 31) * 4;
        #pragma unroll
        for (int i = 0; i < 4; ++i)
            wT1[n * 128 + k + i] = f2b(W1[(size_t)(k + i) * 128 + n]);
    }
}

// ---------------------------------------------------------------- per-bin counting sort -> srt (src grouped by node) + per-node base/cnt
__global__ __launch_bounds__(512)
void bin_sort(const unsigned* __restrict__ gcur, const unsigned* __restrict__ binned,
              unsigned* __restrict__ srt, unsigned* __restrict__ gbase,
              unsigned* __restrict__ ghist)
{
    __shared__ unsigned hist[BINSZ];
    __shared__ unsigned base[BINSZ];
    __shared__ unsigned cur[BINSZ];
    __shared__ unsigned wtot_s;
    const int t = threadIdx.x;
    const int bin = blockIdx.x;

    if (t < BINSZ) hist[t] = 0;
    __syncthreads();

    int cnt = (int)gcur[bin];
    if (cnt > BCAP) cnt = BCAP;
    const unsigned* __restrict__ bp = binned + (size_t)bin * BCAP;

    for (int i = t; i < cnt; i += 512)
        atomicAdd(&hist[(bp[i] >> 17) & (BINSZ - 1)], 1u);
    __syncthreads();
    unsigned iv = 0, hv = 0;
    if (t < BINSZ) {
        hv = hist[t];
        iv = hv;
        #pragma unroll
        for (int d = 1; d < 64; d <<= 1) {
            unsigned u = __shfl_up(iv, d);
            if ((t & 63) >= d) iv += u;
        }
        if (t == 63) wtot_s = iv;
    }
    __syncthreads();
    if (t < BINSZ) {
        unsigned ex = iv - hv + ((t >= 64) ? wtot_s : 0u);
        base[t] = ex;
        cur[t] = ex;
    }
    __syncthreads();
    unsigned* __restrict__ sp = srt + (size_t)bin * BCAP;
    for (int i = t; i < cnt; i += 512) {
        unsigned p = bp[i];
        unsigned pos = atomicAdd(&cur[(p >> 17) & (BINSZ - 1)], 1u);
        sp[pos] = p & 0x1FFFFu;
    }
    if (t < BINSZ) {
        gbase[bin * BINSZ + t] = base[t];
        ghist[bin * BINSZ + t] = hist[t];
    }
}

// ---------------------------------------------------------------- fused gather + GEMM1, HALF-BIN blocks: 64 nodes, 256 thr (4 waves)
// grid = nbins*2. LDS ~17.6 KB -> high residency; gather phases of some blocks
// overlap GEMM phases of others.
__global__ __launch_bounds__(256)
void agg_gemm1(const unsigned short* __restrict__ xb, const float* __restrict__ epsp,
               const unsigned* __restrict__ srt, const unsigned* __restrict__ gbase,
               const unsigned* __restrict__ ghist,
               const unsigned short* __restrict__ wT, const float* __restrict__ bias,
               unsigned short* __restrict__ h1b, float* __restrict__ stats, int N)
{
    __shared__ unsigned short sA[64 * 128];    // 16 KB, swizzled A half-tile
    __shared__ unsigned sbase[64], shist[64];
    __shared__ float red[256];
    const int t = threadIdx.x;
    const int bin  = blockIdx.x >> 1;
    const int half = blockIdx.x & 1;
    const int node0 = (bin << BINSHIFT) + half * 64;
    const int nidx0 = half * 64;               // node offset within bin

    if (t < 64) {
        sbase[t] = gbase[bin * BINSZ + nidx0 + t];
        shist[t] = ghist[bin * BINSZ + nidx0 + t];
    }
    red[t] = 0.f;
    __syncthreads();

    // ---- gather phase: 16 lanes/node x 8 ch, 4 sweeps of 16 nodes -> swizzled sA ----
    const unsigned* __restrict__ spb = srt + (size_t)bin * BCAP;
    const float e = 1.0f + epsp[0];
    const int g8 = t & 15;          // channel chunk 0..15
    const int g  = g8 * 8;
    const int slot = t >> 4;        // 0..15
    for (int sw = 0; sw < 4; ++sw) {
        int dn = sw * 16 + slot;    // node in half-bin (0..63)
        int node = node0 + dn;
        float acc[8];
        if (node < N) {
            bf16x8 v0 = *(const bf16x8*)(xb + (size_t)node * DIM + g);
            #pragma unroll
            for (int q = 0; q < 8; ++q) acc[q] = e * b2f((unsigned short)v0[q]);
            const unsigned* __restrict__ sp = spb + sbase[dn];
            const int hn = (int)shist[dn];
            int j = 0;
            for (; j + 8 <= hn; j += 8) {
                unsigned s0 = sp[j+0], s1 = sp[j+1], s2 = sp[j+2], s3 = sp[j+3];
                unsigned s4 = sp[j+4], s5 = sp[j+5], s6 = sp[j+6], s7 = sp[j+7];
                bf16x8 r0 = *(const bf16x8*)(xb + (size_t)s0 * DIM + g);
                bf16x8 r1 = *(const bf16x8*)(xb + (size_t)s1 * DIM + g);
                bf16x8 r2 = *(const bf16x8*)(xb + (size_t)s2 * DIM + g);
                bf16x8 r3 = *(const bf16x8*)(xb + (size_t)s3 * DIM + g);
                bf16x8 r4 = *(const bf16x8*)(xb + (size_t)s4 * DIM + g);
                bf16x8 r5 = *(const bf16x8*)(xb + (size_t)s5 * DIM + g);
                bf16x8 r6 = *(const bf16x8*)(xb + (size_t)s6 * DIM + g);
                bf16x8 r7 = *(const bf16x8*)(xb + (size_t)s7 * DIM + g);
                #pragma unroll
                for (int q = 0; q < 8; ++q)
                    acc[q] += b2f((unsigned short)r0[q]) + b2f((unsigned short)r1[q])
                            + b2f((unsigned short)r2[q]) + b2f((unsigned short)r3[q])
                            + b2f((unsigned short)r4[q]) + b2f((unsigned short)r5[q])
                            + b2f((unsigned short)r6[q]) + b2f((unsigned short)r7[q]);
            }
            for (; j + 2 <= hn; j += 2) {
                unsigned s0 = sp[j+0], s1 = sp[j+1];
                bf16x8 r0 = *(const bf16x8*)(xb + (size_t)s0 * DIM + g);
                bf16x8 r1 = *(const bf16x8*)(xb + (size_t)s1 * DIM + g);
                #pragma unroll
                for (int q = 0; q < 8; ++q)
                    acc[q] += b2f((unsigned short)r0[q]) + b2f((unsigned short)r1[q]);
            }
            for (; j < hn; ++j) {
                unsigned s0 = sp[j];
                bf16x8 r0 = *(const bf16x8*)(xb + (size_t)s0 * DIM + g);
                #pragma unroll
                for (int q = 0; q < 8; ++q) acc[q] += b2f((unsigned short)r0[q]);
            }
        } else {
            #pragma unroll
            for (int q = 0; q < 8; ++q) acc[q] = 0.f;
        }
        bf16x8 o;
        #pragma unroll
        for (int q = 0; q < 8; ++q) o[q] = (short)f2b(acc[q]);
        // swizzled store: chunk g8 of row dn -> slot (g8 ^ (dn&15))
        *(bf16x8*)&sA[dn * 128 + ((g8 ^ (dn & 15)) << 3)] = o;
    }
    __syncthreads();

    // ---- GEMM phase: 4 waves x 16 rows; A from sA, B-frags from global bf16 W^T ----
    const int lane = t & 63;
    const int wave = t >> 6;               // 0..3
    const int rl   = lane & 15;
    const int kg   = lane >> 4;            // 0..3
    const int r0   = wave * 16;            // row in half-bin

    bf16x8 a0 = *(const bf16x8*)&sA[(r0 + rl) * 128 + (((0 * 4 + kg) ^ rl) << 3)];
    bf16x8 a1 = *(const bf16x8*)&sA[(r0 + rl) * 128 + (((1 * 4 + kg) ^ rl) << 3)];
    bf16x8 a2 = *(const bf16x8*)&sA[(r0 + rl) * 128 + (((2 * 4 + kg) ^ rl) << 3)];
    bf16x8 a3 = *(const bf16x8*)&sA[(r0 + rl) * 128 + (((3 * 4 + kg) ^ rl) << 3)];

    f32x4 c[8];
    #pragma unroll
    for (int nt = 0; nt < 8; ++nt) c[nt] = (f32x4)(0.f);
    #pragma unroll
    for (int nt = 0; nt < 8; ++nt) {
        const unsigned short* wrow = wT + (size_t)(nt * 16 + rl) * DIM + kg * 8;
        bf16x8 w0 = *(const bf16x8*)(wrow + 0);
        bf16x8 w1 = *(const bf16x8*)(wrow + 32);
        bf16x8 w2 = *(const bf16x8*)(wrow + 64);
        bf16x8 w3 = *(const bf16x8*)(wrow + 96);
        c[nt] = __builtin_amdgcn_mfma_f32_16x16x32_bf16(a0, w0, c[nt], 0, 0, 0);
        c[nt] = __builtin_amdgcn_mfma_f32_16x16x32_bf16(a1, w1, c[nt], 0, 0, 0);
        c[nt] = __builtin_amdgcn_mfma_f32_16x16x32_bf16(a2, w2, c[nt], 0, 0, 0);
        c[nt] = __builtin_amdgcn_mfma_f32_16x16x32_bf16(a3, w3, c[nt], 0, 0, 0);
    }

    // epilogue: bias, store h1b (bf16), stats. C layout: col=lane&15, row=(lane>>4)*4+j
    const int orow0 = node0 + r0 + kg * 4;
    #pragma unroll
    for (int nt = 0; nt < 8; ++nt) {
        int n = nt * 16 + rl;
        float bb = bias[n];
        float ls = 0.f, ls2 = 0.f;
        #pragma unroll
        for (int jj = 0; jj < 4; ++jj) {
            int r = orow0 + jj;
            if (r < N) {
                float v = c[nt][jj] + bb;
                h1b[(size_t)r * DIM + n] = f2b(v);
                ls += v; ls2 += v * v;
            }
        }
        ls  += __shfl_xor(ls, 16);  ls  += __shfl_xor(ls, 32);
        ls2 += __shfl_xor(ls2, 16); ls2 += __shfl_xor(ls2, 32);
        if (kg == 0) { atomicAdd(&red[n], ls); atomicAdd(&red[128 + n], ls2); }
    }
    __syncthreads();
    atomicAdd(&stats[t], red[t]);
}

// ---------------------------------------------------------------- MFMA GEMM2 (R9-proven): LDS sWT staging, BN1 finalized in-block, + stats2
__global__ __launch_bounds__(1024)
void gemm2_mfma(const unsigned short* __restrict__ A, const float* __restrict__ Wf,
                const float* __restrict__ bias,
                const float* __restrict__ stats_in, const float* __restrict__ gamma,
                const float* __restrict__ beta, float invN,
                unsigned short* __restrict__ outp, float* __restrict__ stats, int N)
{
    __shared__ unsigned short sWT[128 * 128];
    __shared__ float red[256];
    __shared__ float sss[256];
    const int tid = threadIdx.x;

    if (tid < 128) {
        float mu  = stats_in[tid] * invN;
        float var = fmaxf(stats_in[128 + tid] * invN - mu * mu, 0.f);
        float sc  = gamma[tid] * rsqrtf(var + 1e-5f);
        sss[tid]       = sc;
        sss[128 + tid] = beta[tid] - mu * sc;
    }
    #pragma unroll
    for (int i = 0; i < 4; ++i) {
        int idx = (i * 1024 + tid) * 4;
        float4 w = *(const float4*)&Wf[idx];
        int k = idx >> 7, n0 = idx & 127;
        sWT[(n0 + 0) * 128 + (k ^ (((n0 + 0) & 7) << 3))] = f2b(w.x);
        sWT[(n0 + 1) * 128 + (k ^ (((n0 + 1) & 7) << 3))] = f2b(w.y);
        sWT[(n0 + 2) * 128 + (k ^ (((n0 + 2) & 7) << 3))] = f2b(w.z);
        sWT[(n0 + 3) * 128 + (k ^ (((n0 + 3) & 7) << 3))] = f2b(w.w);
    }
    if (tid < 256) red[tid] = 0.f;
    __syncthreads();

    const int lane = tid & 63;
    const int wave = tid >> 6;
    const int r0   = blockIdx.x * 256 + wave * 16;
    const int rl   = lane & 15;
    const int kg   = lane >> 4;
    int rr = r0 + rl;
    int rclamp = rr < N ? rr : N - 1;
    const unsigned short* arow = A + (size_t)rclamp * DIM + kg * 8;

    f32x4 acc[8];
    #pragma unroll
    for (int nt = 0; nt < 8; ++nt) acc[nt] = (f32x4)(0.f);

    #pragma unroll
    for (int kk = 0; kk < 128; kk += 32) {
        bf16x8 a8 = *(const bf16x8*)(arow + kk);
        {
            const int cb = kk + kg * 8;
            bf16x8 tt;
            #pragma unroll
            for (int j = 0; j < 8; ++j) {
                float f = b2f((unsigned short)a8[j]) * sss[cb + j] + sss[128 + cb + j];
                tt[j] = (short)f2b(fmaxf(f, 0.f));
            }
            a8 = tt;
        }
        const int ks = kk + kg * 8;
        #pragma unroll
        for (int nt = 0; nt < 8; ++nt) {
            int n = nt * 16 + rl;
            bf16x8 b8 = *(const bf16x8*)&sWT[n * 128 + (ks ^ ((n & 7) << 3))];
            acc[nt] = __builtin_amdgcn_mfma_f32_16x16x32_bf16(a8, b8, acc[nt], 0, 0, 0);
        }
    }

    const int orow0 = r0 + kg * 4;
    #pragma unroll
    for (int nt = 0; nt < 8; ++nt) {
        int n = nt * 16 + rl;
        float bb = bias[n];
        float ls = 0.f, ls2 = 0.f;
        #pragma unroll
        for (int j = 0; j < 4; ++j) {
            int r = orow0 + j;
            if (r < N) {
                float v = acc[nt][j] + bb;
                outp[(size_t)r * DIM + n] = f2b(v);
                ls += v; ls2 += v * v;
            }
        }
        ls  += __shfl_xor(ls, 16);  ls  += __shfl_xor(ls, 32);
        ls2 += __shfl_xor(ls2, 16); ls2 += __shfl_xor(ls2, 32);
        if (kg == 0) { atomicAdd(&red[n], ls); atomicAdd(&red[128 + n], ls2); }
    }
    __syncthreads();
    if (tid < 256) atomicAdd(&stats[tid], red[tid]);
}

// ---------------------------------------------------------------- final BN+ReLU: bf16 h2 -> fp32 out, BN finalized in-block
__global__ __launch_bounds__(256)
void bn_relu_out_b(const unsigned short* __restrict__ h2b,
                   const float* __restrict__ stats, const float* __restrict__ gamma,
                   const float* __restrict__ beta, float invN,
                   float* __restrict__ out, int n8)
{
    __shared__ float sss[256];
    const int tid = threadIdx.x;
    if (tid < 128) {
        float mu  = stats[tid] * invN;
        float var = fmaxf(stats[128 + tid] * invN - mu * mu, 0.f);
        float sc  = gamma[tid] * rsqrtf(var + 1e-5f);
        sss[tid]       = sc;
        sss[128 + tid] = beta[tid] - mu * sc;
    }
    __syncthreads();
    int i = blockIdx.x * 256 + tid;
    if (i >= n8) return;
    int c = (i * 8) & 127;
    bf16x8 v = *(const bf16x8*)(h2b + (size_t)i * 8);
    float4 o0, o1;
    o0.x = fmaxf(b2f((unsigned short)v[0]) * sss[c+0] + sss[128+c+0], 0.f);
    o0.y = fmaxf(b2f((unsigned short)v[1]) * sss[c+1] + sss[128+c+1], 0.f);
    o0.z = fmaxf(b2f((unsigned short)v[2]) * sss[c+2] + sss[128+c+2], 0.f);
    o0.w = fmaxf(b2f((unsigned short)v[3]) * sss[c+3] + sss[128+c+3], 0.f);
    o1.x = fmaxf(b2f((unsigned short)v[4]) * sss[c+4] + sss[128+c+4], 0.f);
    o1.y = fmaxf(b2f((unsigned short)v[5]) * sss[c+5] + sss[128+c+5], 0.f);
    o1.z = fmaxf(b2f((unsigned short)v[6]) * sss[c+6] + sss[128+c+6], 0.f);
    o1.w = fmaxf(b2f((unsigned short)v[7]) * sss[c+7] + sss[128+c+7], 0.f);
    ((float4*)out)[i * 2 + 0] = o0;
    ((float4*)out)[i * 2 + 1] = o1;
}

// ----------------------------------------------------------------
extern "C" void kernel_launch(void* const* d_in, const int* in_sizes, int n_in,
                              void* d_out, int out_size, void* d_ws, size_t ws_size,
                              hipStream_t stream) {
    const float* x    = (const float*)d_in[0];
    const int*   ei   = (const int*)  d_in[1];
    const float* W1   = (const float*)d_in[2];
    const float* b1   = (const float*)d_in[3];
    const float* g1   = (const float*)d_in[4];
    const float* be1  = (const float*)d_in[5];
    const float* W2   = (const float*)d_in[6];
    const float* b2   = (const float*)d_in[7];
    const float* g2   = (const float*)d_in[8];
    const float* be2  = (const float*)d_in[9];
    const float* epsp = (const float*)d_in[10];
    float* out = (float*)d_out;

    const int N = in_sizes[0] / DIM;   // 100000
    const int E = in_sizes[1] / 2;     // 1600000
    const int* src = ei;
    const int* dst = ei + E;
    const int nbins = (N + BINSZ - 1) >> BINSHIFT;   // 782

    // workspace layout (~76.9 MB):
    //   [0]     xb  [N*128 ushort]  25.6 MB
    //   [SZ]    h1b [N*128 ushort]  25.6 MB
    //   [2SZ]   regC: binned(8MB) | srt(8MB) | gbase(.4) | ghist(.4)  (dead after agg_gemm1)
    //           h2b overlays regC
    //   [3SZ]   gcur[1024 u32] | stats1[256 f] | stats2[256 f] | wT1[16384 bf16]
    const size_t SZ = (size_t)N * DIM * sizeof(unsigned short);
    char* w = (char*)d_ws;
    unsigned short* xb  = (unsigned short*)w;
    unsigned short* h1b = (unsigned short*)(w + SZ);
    unsigned* binned    = (unsigned*)(w + 2 * SZ);
    unsigned* srt       = binned + (size_t)nbins * BCAP;
    unsigned* gbase     = srt + (size_t)nbins * BCAP;
    unsigned* ghist     = gbase + (size_t)nbins * BINSZ;
    unsigned short* h2b = (unsigned short*)(w + 2 * SZ);
    unsigned* gcur      = (unsigned*)(w + 3 * SZ);
    float* stats1 = (float*)(gcur + 1024);
    float* stats2 = stats1 + 256;
    unsigned short* wT1 = (unsigned short*)(stats2 + 256);

    const float invN = 1.0f / (float)N;
    const int n8 = N * DIM / 8;
    const int ebB = (E + EPB - 1) / EPB;            // 196 binning blocks
    const int castB = (n8 + 1023) / 1024;           // 1563 cast blocks

    // 1: zero gcur+stats1+stats2 (contiguous)
    hipMemsetAsync(gcur, 0, (1024 + 512) * sizeof(unsigned), stream);
    // 2: bin edges + cast x + transpose/cast W1 (one kernel, roles by blockIdx)
    prep<<<ebB + castB + 4, 1024, 0, stream>>>(src, dst, gcur, binned, E, nbins,
                                               x, xb, n8, W1, wT1, ebB, castB);
    // 3: per-bin counting sort -> global CSR
    bin_sort<<<nbins, 512, 0, stream>>>(gcur, binned, srt, gbase, ghist);
    // 4: fused gather->LDS + GEMM1 + stats1 (half-bin blocks: 1564 x 256 thr)
    agg_gemm1<<<nbins * 2, 256, 0, stream>>>(xb, epsp, srt, gbase, ghist, wT1, b1, h1b, stats1, N);
    // 5: GEMM2 (BN1+ReLU fused on input) + stats2
    const int gblocks = (N + 255) / 256;
    gemm2_mfma<<<gblocks, 1024, 0, stream>>>(h1b, W2, b2, stats1, g1, be1, invN, h2b, stats2, N);
    // 6: BN2+ReLU -> fp32 out
    bn_relu_out_b<<<(n8 + 255) / 256, 256, 0, stream>>>(h2b, stats2, g2, be2, invN, out, n8);
}

// Round 13
// 185.105 us; speedup vs baseline: 1.1337x; 1.1337x over previous
//
#include <hip/hip_runtime.h>

#define DIM 128
#define BINSHIFT 7
#define BINSZ 128          // nodes per bin
#define BCAP 2560          // edges capacity per bin: Poisson(2048)+11sigma
#define EPB 8192           // edges per binning block

typedef __attribute__((ext_vector_type(8))) short bf16x8;
typedef __attribute__((ext_vector_type(4))) float f32x4;

__device__ inline unsigned short f2b(float f) {
    unsigned u = __builtin_bit_cast(unsigned, f);
    unsigned r = (u + 0x7FFFu + ((u >> 16) & 1u)) >> 16;
    return (unsigned short)r;
}
__device__ inline float b2f(unsigned short h) {
    unsigned u = ((unsigned)h) << 16;
    return __builtin_bit_cast(float, u);
}

// ---------------------------------------------------------------- prep: [0,ebB) bin edges | [ebB,..) cast x->bf16
__global__ __launch_bounds__(1024)
void prep(const int* __restrict__ src, const int* __restrict__ dst,
          unsigned* __restrict__ gcur, unsigned* __restrict__ binned, int E, int nbins,
          const float* __restrict__ x, unsigned short* __restrict__ xb, int n8, int ebB)
{
    const int t = threadIdx.x;
    const int bid = blockIdx.x;
    if (bid < ebB) {
        // ---- binning role (proven) ----
        __shared__ unsigned hist[1024];
        __shared__ unsigned base[1024];
        const long long bb = (long long)bid * EPB;
        if (t < nbins) hist[t] = 0;
        __syncthreads();
        unsigned pk[8], pos[8];
        int bn[8];
        bool ok[8];
        #pragma unroll
        for (int i = 0; i < 8; ++i) {
            long long idx = bb + i * 1024 + t;
            ok[i] = idx < E;
            if (ok[i]) {
                int s = src[idx], d = dst[idx];
                pk[i] = ((unsigned)(d & (BINSZ - 1)) << 17) | (unsigned)s;
                bn[i] = d >> BINSHIFT;
                pos[i] = atomicAdd(&hist[bn[i]], 1u);
            }
        }
        __syncthreads();
        if (t < nbins) base[t] = (unsigned)t * BCAP + atomicAdd(&gcur[t], hist[t]);
        __syncthreads();
        #pragma unroll
        for (int i = 0; i < 8; ++i) {
            if (ok[i]) {
                unsigned off = base[bn[i]] + pos[i];
                if (off < (unsigned)(bn[i] + 1) * BCAP) binned[off] = pk[i];
            }
        }
    } else {
        // ---- cast role ----
        int i = (bid - ebB) * 1024 + t;
        if (i >= n8) return;
        float4 a = ((const float4*)x)[i * 2];
        float4 b = ((const float4*)x)[i * 2 + 1];
        bf16x8 o;
        o[0] = (short)f2b(a.x); o[1] = (short)f2b(a.y); o[2] = (short)f2b(a.z); o[3] = (short)f2b(a.w);
        o[4] = (short)f2b(b.x); o[5] = (short)f2b(b.y); o[6] = (short)f2b(b.z); o[7] = (short)f2b(b.w);
        ((bf16x8*)xb)[i] = o;
    }
}

// ---------------------------------------------------------------- per-bin counting sort -> srt (src grouped by node) + per-node base/cnt
__global__ __launch_bounds__(512)
void bin_sort(const unsigned* __restrict__ gcur, const unsigned* __restrict__ binned,
              unsigned* __restrict__ srt, unsigned* __restrict__ gbase,
              unsigned* __restrict__ ghist)
{
    __shared__ unsigned hist[BINSZ];
    __shared__ unsigned base[BINSZ];
    __shared__ unsigned cur[BINSZ];
    __shared__ unsigned wtot_s;
    const int t = threadIdx.x;
    const int bin = blockIdx.x;

    if (t < BINSZ) hist[t] = 0;
    __syncthreads();

    int cnt = (int)gcur[bin];
    if (cnt > BCAP) cnt = BCAP;
    const unsigned* __restrict__ bp = binned + (size_t)bin * BCAP;

    for (int i = t; i < cnt; i += 512)
        atomicAdd(&hist[(bp[i] >> 17) & (BINSZ - 1)], 1u);
    __syncthreads();
    // parallel exclusive scan (two waves, shfl_up)
    unsigned iv = 0, hv = 0;
    if (t < BINSZ) {
        hv = hist[t];
        iv = hv;
        #pragma unroll
        for (int d = 1; d < 64; d <<= 1) {
            unsigned u = __shfl_up(iv, d);
            if ((t & 63) >= d) iv += u;
        }
        if (t == 63) wtot_s = iv;
    }
    __syncthreads();
    if (t < BINSZ) {
        unsigned ex = iv - hv + ((t >= 64) ? wtot_s : 0u);
        base[t] = ex;
        cur[t] = ex;
    }
    __syncthreads();
    unsigned* __restrict__ sp = srt + (size_t)bin * BCAP;
    for (int i = t; i < cnt; i += 512) {
        unsigned p = bp[i];
        unsigned pos = atomicAdd(&cur[(p >> 17) & (BINSZ - 1)], 1u);
        sp[pos] = p & 0x1FFFFu;
    }
    if (t < BINSZ) {
        gbase[bin * BINSZ + t] = base[t];   // indexed by node id
        ghist[bin * BINSZ + t] = hist[t];
    }
}

// ---------------------------------------------------------------- CSR gather (R7-proven best): 32 nodes/block, 16 lanes/node x 8 ch, 4-wide ILP
__global__ __launch_bounds__(512)
void gather_csr(const unsigned short* __restrict__ xb, const float* __restrict__ epsp,
                const unsigned* __restrict__ srt, const unsigned* __restrict__ gbase,
                const unsigned* __restrict__ ghist,
                unsigned short* __restrict__ h0b, int N)
{
    const int t = threadIdx.x;
    const int node = blockIdx.x * 32 + (t >> 4);
    if (node >= N) return;
    const int g = (t & 15) * 8;
    const float e = 1.0f + epsp[0];

    bf16x8 v0 = *(const bf16x8*)(xb + (size_t)node * DIM + g);
    float acc[8];
    #pragma unroll
    for (int q = 0; q < 8; ++q) acc[q] = e * b2f((unsigned short)v0[q]);

    const int b0 = (int)gbase[node];
    const int hn = (int)ghist[node];
    const unsigned* __restrict__ sp = srt + (size_t)(node >> BINSHIFT) * BCAP + b0;

    int j = 0;
    for (; j + 4 <= hn; j += 4) {
        unsigned s0 = sp[j + 0];
        unsigned s1 = sp[j + 1];
        unsigned s2 = sp[j + 2];
        unsigned s3 = sp[j + 3];
        bf16x8 r0 = *(const bf16x8*)(xb + (size_t)s0 * DIM + g);
        bf16x8 r1 = *(const bf16x8*)(xb + (size_t)s1 * DIM + g);
        bf16x8 r2 = *(const bf16x8*)(xb + (size_t)s2 * DIM + g);
        bf16x8 r3 = *(const bf16x8*)(xb + (size_t)s3 * DIM + g);
        #pragma unroll
        for (int q = 0; q < 8; ++q)
            acc[q] += b2f((unsigned short)r0[q]) + b2f((unsigned short)r1[q])
                    + b2f((unsigned short)r2[q]) + b2f((unsigned short)r3[q]);
    }
    for (; j < hn; ++j) {
        unsigned s0 = sp[j];
        bf16x8 r0 = *(const bf16x8*)(xb + (size_t)s0 * DIM + g);
        #pragma unroll
        for (int q = 0; q < 8; ++q) acc[q] += b2f((unsigned short)r0[q]);
    }
    bf16x8 o;
    #pragma unroll
    for (int q = 0; q < 8; ++q) o[q] = (short)f2b(acc[q]);
    *(bf16x8*)(h0b + (size_t)node * DIM + g) = o;
}

// ---------------------------------------------------------------- MFMA GEMM (R8-proven): LDS sWT staging; APPLY_BN finalizes BN in-block
template<bool APPLY_BN>
__global__ __launch_bounds__(1024)
void gemm_mfma(const unsigned short* __restrict__ A, const float* __restrict__ Wf,
               const float* __restrict__ bias,
               const float* __restrict__ stats_in, const float* __restrict__ gamma,
               const float* __restrict__ beta, float invN,
               unsigned short* __restrict__ outp, float* __restrict__ stats, int N)
{
    __shared__ unsigned short sWT[128 * 128];  // swizzled W^T (bf16), 32 KB
    __shared__ float red[256];
    __shared__ float sss[256];
    const int tid = threadIdx.x;

    if (APPLY_BN && tid < 128) {
        float mu  = stats_in[tid] * invN;
        float var = fmaxf(stats_in[128 + tid] * invN - mu * mu, 0.f);
        float sc  = gamma[tid] * rsqrtf(var + 1e-5f);
        sss[tid]       = sc;
        sss[128 + tid] = beta[tid] - mu * sc;
    }
    #pragma unroll
    for (int i = 0; i < 4; ++i) {
        int idx = (i * 1024 + tid) * 4;
        float4 w = *(const float4*)&Wf[idx];
        int k = idx >> 7, n0 = idx & 127;
        sWT[(n0 + 0) * 128 + (k ^ (((n0 + 0) & 7) << 3))] = f2b(w.x);
        sWT[(n0 + 1) * 128 + (k ^ (((n0 + 1) & 7) << 3))] = f2b(w.y);
        sWT[(n0 + 2) * 128 + (k ^ (((n0 + 2) & 7) << 3))] = f2b(w.z);
        sWT[(n0 + 3) * 128 + (k ^ (((n0 + 3) & 7) << 3))] = f2b(w.w);
    }
    if (tid < 256) red[tid] = 0.f;
    __syncthreads();

    const int lane = tid & 63;
    const int wave = tid >> 6;
    const int r0   = blockIdx.x * 256 + wave * 16;
    const int rl   = lane & 15;
    const int kg   = lane >> 4;
    int rr = r0 + rl;
    int rclamp = rr < N ? rr : N - 1;
    const unsigned short* arow = A + (size_t)rclamp * DIM + kg * 8;

    f32x4 acc[8];
    #pragma unroll
    for (int nt = 0; nt < 8; ++nt) acc[nt] = (f32x4)(0.f);

    #pragma unroll
    for (int kk = 0; kk < 128; kk += 32) {
        bf16x8 a8 = *(const bf16x8*)(arow + kk);
        if (APPLY_BN) {
            const int cb = kk + kg * 8;
            bf16x8 tt;
            #pragma unroll
            for (int j = 0; j < 8; ++j) {
                float f = b2f((unsigned short)a8[j]) * sss[cb + j] + sss[128 + cb + j];
                tt[j] = (short)f2b(fmaxf(f, 0.f));
            }
            a8 = tt;
        }
        const int ks = kk + kg * 8;
        #pragma unroll
        for (int nt = 0; nt < 8; ++nt) {
            int n = nt * 16 + rl;
            bf16x8 b8 = *(const bf16x8*)&sWT[n * 128 + (ks ^ ((n & 7) << 3))];
            acc[nt] = __builtin_amdgcn_mfma_f32_16x16x32_bf16(a8, b8, acc[nt], 0, 0, 0);
        }
    }

    const int orow0 = r0 + kg * 4;
    #pragma unroll
    for (int nt = 0; nt < 8; ++nt) {
        int n = nt * 16 + rl;
        float bb = bias[n];
        float ls = 0.f, ls2 = 0.f;
        #pragma unroll
        for (int j = 0; j < 4; ++j) {
            int r = orow0 + j;
            if (r < N) {
                float v = acc[nt][j] + bb;
                outp[(size_t)r * DIM + n] = f2b(v);
                ls += v; ls2 += v * v;
            }
        }
        ls  += __shfl_xor(ls, 16);  ls  += __shfl_xor(ls, 32);
        ls2 += __shfl_xor(ls2, 16); ls2 += __shfl_xor(ls2, 32);
        if (kg == 0) { atomicAdd(&red[n], ls); atomicAdd(&red[128 + n], ls2); }
    }
    __syncthreads();
    if (tid < 256) atomicAdd(&stats[tid], red[tid]);
}

// ---------------------------------------------------------------- final BN+ReLU: bf16 h2 -> fp32 out, BN finalized in-block
__global__ __launch_bounds__(256)
void bn_relu_out_b(const unsigned short* __restrict__ h2b,
                   const float* __restrict__ stats, const float* __restrict__ gamma,
                   const float* __restrict__ beta, float invN,
                   float* __restrict__ out, int n8)
{
    __shared__ float sss[256];
    const int tid = threadIdx.x;
    if (tid < 128) {
        float mu  = stats[tid] * invN;
        float var = fmaxf(stats[128 + tid] * invN - mu * mu, 0.f);
        float sc  = gamma[tid] * rsqrtf(var + 1e-5f);
        sss[tid]       = sc;
        sss[128 + tid] = beta[tid] - mu * sc;
    }
    __syncthreads();
    int i = blockIdx.x * 256 + tid;
    if (i >= n8) return;
    int c = (i * 8) & 127;
    bf16x8 v = *(const bf16x8*)(h2b + (size_t)i * 8);
    float4 o0, o1;
    o0.x = fmaxf(b2f((unsigned short)v[0]) * sss[c+0] + sss[128+c+0], 0.f);
    o0.y = fmaxf(b2f((unsigned short)v[1]) * sss[c+1] + sss[128+c+1], 0.f);
    o0.z = fmaxf(b2f((unsigned short)v[2]) * sss[c+2] + sss[128+c+2], 0.f);
    o0.w = fmaxf(b2f((unsigned short)v[3]) * sss[c+3] + sss[128+c+3], 0.f);
    o1.x = fmaxf(b2f((unsigned short)v[4]) * sss[c+4] + sss[128+c+4], 0.f);
    o1.y = fmaxf(b2f((unsigned short)v[5]) * sss[c+5] + sss[128+c+5], 0.f);
    o1.z = fmaxf(b2f((unsigned short)v[6]) * sss[c+6] + sss[128+c+6], 0.f);
    o1.w = fmaxf(b2f((unsigned short)v[7]) * sss[c+7] + sss[128+c+7], 0.f);
    ((float4*)out)[i * 2 + 0] = o0;
    ((float4*)out)[i * 2 + 1] = o1;
}

// ----------------------------------------------------------------
extern "C" void kernel_launch(void* const* d_in, const int* in_sizes, int n_in,
                              void* d_out, int out_size, void* d_ws, size_t ws_size,
                              hipStream_t stream) {
    const float* x    = (const float*)d_in[0];
    const int*   ei   = (const int*)  d_in[1];
    const float* W1   = (const float*)d_in[2];
    const float* b1   = (const float*)d_in[3];
    const float* g1   = (const float*)d_in[4];
    const float* be1  = (const float*)d_in[5];
    const float* W2   = (const float*)d_in[6];
    const float* b2   = (const float*)d_in[7];
    const float* g2   = (const float*)d_in[8];
    const float* be2  = (const float*)d_in[9];
    const float* epsp = (const float*)d_in[10];
    float* out = (float*)d_out;

    const int N = in_sizes[0] / DIM;   // 100000
    const int E = in_sizes[1] / 2;     // 1600000
    const int* src = ei;
    const int* dst = ei + E;
    const int nbins = (N + BINSZ - 1) >> BINSHIFT;   // 782

    // workspace layout (~76.8 MB + tail):
    //   [0]     xb  [N*128 ushort]  25.6 MB
    //   [SZ]    h0b [N*128 ushort]  25.6 MB   (h2b overlays: h0b dead after gemm1)
    //   [2SZ]   regC (25.6 MB): binned(8) | srt(8) | gbase(.4) | ghist(.4) | pad
    //           h1b overlays regC (binned/srt/gbase/ghist dead before h1b written)
    //   [3SZ]   tail: gcur[1024 u32] | stats1[256 f] | stats2[256 f]
    const size_t SZ = (size_t)N * DIM * sizeof(unsigned short);
    char* w = (char*)d_ws;
    unsigned short* xb  = (unsigned short*)w;
    unsigned short* h0b = (unsigned short*)(w + SZ);
    unsigned short* h2b = h0b;
    unsigned short* h1b = (unsigned short*)(w + 2 * SZ);
    unsigned* binned = (unsigned*)(w + 2 * SZ);
    unsigned* srt    = binned + (size_t)nbins * BCAP;
    unsigned* gbase  = srt + (size_t)nbins * BCAP;
    unsigned* ghist  = gbase + (size_t)nbins * BINSZ;
    unsigned* gcur   = (unsigned*)(w + 3 * SZ);
    float* stats1 = (float*)(gcur + 1024);
    float* stats2 = stats1 + 256;

    const float invN = 1.0f / (float)N;
    const int n8 = N * DIM / 8;
    const int ebB = (E + EPB - 1) / EPB;            // 196 binning blocks
    const int castB = (n8 + 1023) / 1024;           // 1563 cast blocks

    // 1: zero gcur+stats1+stats2 (contiguous)
    hipMemsetAsync(gcur, 0, (1024 + 512) * sizeof(unsigned), stream);
    // 2: bin edges + cast x->bf16 (merged, roles by blockIdx)
    prep<<<ebB + castB, 1024, 0, stream>>>(src, dst, gcur, binned, E, nbins, x, xb, n8, ebB);
    // 3: per-bin counting sort -> global CSR
    bin_sort<<<nbins, 512, 0, stream>>>(gcur, binned, srt, gbase, ghist);
    // 4: gather (R7-proven best variant)
    gather_csr<<<(N + 31) / 32, 512, 0, stream>>>(xb, epsp, srt, gbase, ghist, h0b, N);
    // 5: layer 1 GEMM + stats1
    const int gblocks = (N + 255) / 256;
    gemm_mfma<false><<<gblocks, 1024, 0, stream>>>(
        h0b, W1, b1, nullptr, nullptr, nullptr, invN, h1b, stats1, N);
    // 6: layer 2 GEMM (BN1+ReLU fused on input, finalized in-block) + stats2
    gemm_mfma<true><<<gblocks, 1024, 0, stream>>>(
        h1b, W2, b2, stats1, g1, be1, invN, h2b, stats2, N);
    // 7: BN2+ReLU -> fp32 out
    bn_relu_out_b<<<(n8 + 255) / 256, 256, 0, stream>>>(h2b, stats2, g2, be2, invN, out, n8);
}

// Round 14
// 179.539 us; speedup vs baseline: 1.1688x; 1.0310x over previous
//
#include <hip/hip_runtime.h>

#define DIM 128
#define BINSHIFT 7
#define BINSZ 128          // nodes per bin
#define BCAP 2560          // edges capacity per bin: Poisson(2048)+11sigma
#define EPB 8192           // edges per binning block

typedef __attribute__((ext_vector_type(8))) short bf16x8;
typedef __attribute__((ext_vector_type(4))) float f32x4;

__device__ inline unsigned short f2b(float f) {
    unsigned u = __builtin_bit_cast(unsigned, f);
    unsigned r = (u + 0x7FFFu + ((u >> 16) & 1u)) >> 16;
    return (unsigned short)r;
}
__device__ inline float b2f(unsigned short h) {
    unsigned u = ((unsigned)h) << 16;
    return __builtin_bit_cast(float, u);
}

// ---------------------------------------------------------------- prep: blocks [0,ebB) bin edges; blocks [ebB,..) cast x->bf16
__global__ __launch_bounds__(1024)
void prep(const int* __restrict__ src, const int* __restrict__ dst,
          unsigned* __restrict__ gcur, unsigned* __restrict__ binned, int E, int nbins,
          const float* __restrict__ x, unsigned short* __restrict__ xb, int n8, int ebB)
{
    const int t = threadIdx.x;
    if (blockIdx.x < ebB) {
        // ---- binning role ----
        __shared__ unsigned hist[1024];
        __shared__ unsigned base[1024];
        const long long bb = (long long)blockIdx.x * EPB;
        if (t < nbins) hist[t] = 0;
        __syncthreads();

        unsigned pk[8], pos[8];
        int bn[8];
        bool ok[8];
        #pragma unroll
        for (int i = 0; i < 8; ++i) {
            long long idx = bb + i * 1024 + t;
            ok[i] = idx < E;
            if (ok[i]) {
                int s = src[idx], d = dst[idx];
                pk[i] = ((unsigned)(d & (BINSZ - 1)) << 17) | (unsigned)s;
                bn[i] = d >> BINSHIFT;
                pos[i] = atomicAdd(&hist[bn[i]], 1u);
            }
        }
        __syncthreads();
        if (t < nbins) base[t] = (unsigned)t * BCAP + atomicAdd(&gcur[t], hist[t]);
        __syncthreads();
        #pragma unroll
        for (int i = 0; i < 8; ++i) {
            if (ok[i]) {
                unsigned off = base[bn[i]] + pos[i];
                if (off < (unsigned)(bn[i] + 1) * BCAP) binned[off] = pk[i];
            }
        }
    } else {
        // ---- cast role ----
        int i = (blockIdx.x - ebB) * 1024 + t;
        if (i >= n8) return;
        float4 a = ((const float4*)x)[i * 2];
        float4 b = ((const float4*)x)[i * 2 + 1];
        bf16x8 o;
        o[0] = (short)f2b(a.x); o[1] = (short)f2b(a.y); o[2] = (short)f2b(a.z); o[3] = (short)f2b(a.w);
        o[4] = (short)f2b(b.x); o[5] = (short)f2b(b.y); o[6] = (short)f2b(b.z); o[7] = (short)f2b(b.w);
        ((bf16x8*)xb)[i] = o;
    }
}

// ---------------------------------------------------------------- fused: per-bin counting sort (LDS) + gather (-> swizzled LDS A) + GEMM1
// 512 threads, one bin of 128 nodes per block. (R9-proven; scan -> shfl version)
__global__ __launch_bounds__(512, 4)
void agg_gemm1(const unsigned short* __restrict__ xb, const float* __restrict__ epsp,
               const unsigned* __restrict__ gcur, const unsigned* __restrict__ binned,
               const float* __restrict__ Wf, const float* __restrict__ bias,
               unsigned short* __restrict__ h1b, float* __restrict__ stats, int N)
{
    __shared__ unsigned short sWT[128 * 128];  // 32 KB, swizzled W^T
    __shared__ unsigned short sA[128 * 128];   // 32 KB, swizzled A tile
    __shared__ unsigned ssrt[BCAP];            // 10 KB
    __shared__ unsigned hist[BINSZ], sbase[BINSZ], cur[BINSZ];
    __shared__ unsigned wtot_s;
    __shared__ float red[256];
    const int t = threadIdx.x;
    const int bin = blockIdx.x;
    const int node0 = bin << BINSHIFT;

    // stage W: row-major [k][n] fp32 -> swizzled W^T bf16 (proven pattern)
    #pragma unroll
    for (int i = 0; i < 8; ++i) {
        int idx = (i * 512 + t) * 4;
        float4 wv = *(const float4*)&Wf[idx];
        int k = idx >> 7, n0 = idx & 127;
        sWT[(n0 + 0) * 128 + (k ^ (((n0 + 0) & 7) << 3))] = f2b(wv.x);
        sWT[(n0 + 1) * 128 + (k ^ (((n0 + 1) & 7) << 3))] = f2b(wv.y);
        sWT[(n0 + 2) * 128 + (k ^ (((n0 + 2) & 7) << 3))] = f2b(wv.z);
        sWT[(n0 + 3) * 128 + (k ^ (((n0 + 3) & 7) << 3))] = f2b(wv.w);
    }
    if (t < BINSZ) hist[t] = 0;
    if (t < 256) red[t] = 0.f;
    __syncthreads();

    // ---- sort phase (counting sort into LDS) ----
    int cnt = (int)gcur[bin];
    if (cnt > BCAP) cnt = BCAP;
    const unsigned* __restrict__ bp = binned + (size_t)bin * BCAP;
    for (int i = t; i < cnt; i += 512)
        atomicAdd(&hist[(bp[i] >> 17) & (BINSZ - 1)], 1u);
    __syncthreads();
    // parallel exclusive scan of hist[128] (two waves, shfl_up) — proven in bin_sort
    unsigned iv = 0, hv = 0;
    if (t < BINSZ) {
        hv = hist[t];
        iv = hv;
        #pragma unroll
        for (int d = 1; d < 64; d <<= 1) {
            unsigned u = __shfl_up(iv, d);
            if ((t & 63) >= d) iv += u;
        }
        if (t == 63) wtot_s = iv;
    }
    __syncthreads();
    if (t < BINSZ) {
        unsigned ex = iv - hv + ((t >= 64) ? wtot_s : 0u);
        sbase[t] = ex;
        cur[t] = ex;
    }
    __syncthreads();
    for (int i = t; i < cnt; i += 512) {
        unsigned p = bp[i];
        unsigned pos = atomicAdd(&cur[(p >> 17) & (BINSZ - 1)], 1u);
        ssrt[pos] = p & 0x1FFFFu;
    }
    __syncthreads();

    // ---- gather phase: 16 lanes/node x 8 ch, 4 sweeps of 32 nodes -> swizzled sA ----
    const float e = 1.0f + epsp[0];
    const int g8 = t & 15;          // channel chunk 0..15
    const int g  = g8 * 8;
    const int slot = t >> 4;        // 0..31
    for (int sw = 0; sw < 4; ++sw) {
        int dn = sw * 32 + slot;
        int node = node0 + dn;
        float acc[8];
        if (node < N) {
            bf16x8 v0 = *(const bf16x8*)(xb + (size_t)node * DIM + g);
            #pragma unroll
            for (int q = 0; q < 8; ++q) acc[q] = e * b2f((unsigned short)v0[q]);
            const int b0 = (int)sbase[dn], hn = (int)hist[dn];
            int j = 0;
            for (; j + 8 <= hn; j += 8) {
                unsigned s0 = ssrt[b0+j+0], s1 = ssrt[b0+j+1], s2 = ssrt[b0+j+2], s3 = ssrt[b0+j+3];
                unsigned s4 = ssrt[b0+j+4], s5 = ssrt[b0+j+5], s6 = ssrt[b0+j+6], s7 = ssrt[b0+j+7];
                bf16x8 r0 = *(const bf16x8*)(xb + (size_t)s0 * DIM + g);
                bf16x8 r1 = *(const bf16x8*)(xb + (size_t)s1 * DIM + g);
                bf16x8 r2 = *(const bf16x8*)(xb + (size_t)s2 * DIM + g);
                bf16x8 r3 = *(const bf16x8*)(xb + (size_t)s3 * DIM + g);
                bf16x8 r4 = *(const bf16x8*)(xb + (size_t)s4 * DIM + g);
                bf16x8 r5 = *(const bf16x8*)(xb + (size_t)s5 * DIM + g);
                bf16x8 r6 = *(const bf16x8*)(xb + (size_t)s6 * DIM + g);
                bf16x8 r7 = *(const bf16x8*)(xb + (size_t)s7 * DIM + g);
                #pragma unroll
                for (int q = 0; q < 8; ++q)
                    acc[q] += b2f((unsigned short)r0[q]) + b2f((unsigned short)r1[q])
                            + b2f((unsigned short)r2[q]) + b2f((unsigned short)r3[q])
                            + b2f((unsigned short)r4[q]) + b2f((unsigned short)r5[q])
                            + b2f((unsigned short)r6[q]) + b2f((unsigned short)r7[q]);
            }
            for (; j + 2 <= hn; j += 2) {
                unsigned s0 = ssrt[b0+j+0], s1 = ssrt[b0+j+1];
                bf16x8 r0 = *(const bf16x8*)(xb + (size_t)s0 * DIM + g);
                bf16x8 r1 = *(const bf16x8*)(xb + (size_t)s1 * DIM + g);
                #pragma unroll
                for (int q = 0; q < 8; ++q)
                    acc[q] += b2f((unsigned short)r0[q]) + b2f((unsigned short)r1[q]);
            }
            for (; j < hn; ++j) {
                unsigned s0 = ssrt[b0+j];
                bf16x8 r0 = *(const bf16x8*)(xb + (size_t)s0 * DIM + g);
                #pragma unroll
                for (int q = 0; q < 8; ++q) acc[q] += b2f((unsigned short)r0[q]);
            }
        } else {
            #pragma unroll
            for (int q = 0; q < 8; ++q) acc[q] = 0.f;
        }
        bf16x8 o;
        #pragma unroll
        for (int q = 0; q < 8; ++q) o[q] = (short)f2b(acc[q]);
        // swizzled store: chunk g8 of row dn -> slot (g8 ^ (dn&15))
        *(bf16x8*)&sA[dn * 128 + ((g8 ^ (dn & 15)) << 3)] = o;
    }
    __syncthreads();

    // ---- GEMM phase: 8 waves x 16 rows ----
    const int lane = t & 63;
    const int wave = t >> 6;               // 0..7
    const int rl   = lane & 15;
    const int kg   = lane >> 4;            // 0..3
    const int r0   = wave * 16;            // row-in-bin

    f32x4 acc[8];
    #pragma unroll
    for (int nt = 0; nt < 8; ++nt) acc[nt] = (f32x4)(0.f);

    #pragma unroll
    for (int kk = 0; kk < 4; ++kk) {
        // A frag: row r0+rl, chunk (kk*4+kg), de-swizzle with ^rl (row&15 == rl)
        bf16x8 a8 = *(const bf16x8*)&sA[(r0 + rl) * 128 + (((kk * 4 + kg) ^ rl) << 3)];
        const int ks = kk * 32 + kg * 8;
        #pragma unroll
        for (int nt = 0; nt < 8; ++nt) {
            int n = nt * 16 + rl;
            bf16x8 b8 = *(const bf16x8*)&sWT[n * 128 + (ks ^ ((n & 7) << 3))];
            acc[nt] = __builtin_amdgcn_mfma_f32_16x16x32_bf16(a8, b8, acc[nt], 0, 0, 0);
        }
    }

    const int orow0 = node0 + r0 + kg * 4;
    #pragma unroll
    for (int nt = 0; nt < 8; ++nt) {
        int n = nt * 16 + rl;
        float bb = bias[n];
        float ls = 0.f, ls2 = 0.f;
        #pragma unroll
        for (int j = 0; j < 4; ++j) {
            int r = orow0 + j;
            if (r < N) {
                float v = acc[nt][j] + bb;
                h1b[(size_t)r * DIM + n] = f2b(v);
                ls += v; ls2 += v * v;
            }
        }
        ls  += __shfl_xor(ls, 16);  ls  += __shfl_xor(ls, 32);
        ls2 += __shfl_xor(ls2, 16); ls2 += __shfl_xor(ls2, 32);
        if (kg == 0) { atomicAdd(&red[n], ls); atomicAdd(&red[128 + n], ls2); }
    }
    __syncthreads();
    if (t < 256) atomicAdd(&stats[t], red[t]);
}

// ---------------------------------------------------------------- MFMA GEMM + bias + BN-stats; APPLY_BN finalizes BN in-block from stats_in
template<bool APPLY_BN, bool OUT_BF16>
__global__ __launch_bounds__(1024)
void gemm_mfma(const unsigned short* __restrict__ A, const float* __restrict__ Wf,
               const float* __restrict__ bias,
               const float* __restrict__ stats_in, const float* __restrict__ gamma,
               const float* __restrict__ beta, float invN,
               void* __restrict__ outp, float* __restrict__ stats, int N)
{
    __shared__ unsigned short sWT[128 * 128];
    __shared__ float red[256];
    __shared__ float sss[256];
    const int tid = threadIdx.x;

    if (APPLY_BN && tid < 128) {
        float mu  = stats_in[tid] * invN;
        float var = fmaxf(stats_in[128 + tid] * invN - mu * mu, 0.f);
        float sc  = gamma[tid] * rsqrtf(var + 1e-5f);
        sss[tid]       = sc;
        sss[128 + tid] = beta[tid] - mu * sc;
    }
    #pragma unroll
    for (int i = 0; i < 4; ++i) {
        int idx = (i * 1024 + tid) * 4;
        float4 w = *(const float4*)&Wf[idx];
        int k = idx >> 7, n0 = idx & 127;
        sWT[(n0 + 0) * 128 + (k ^ (((n0 + 0) & 7) << 3))] = f2b(w.x);
        sWT[(n0 + 1) * 128 + (k ^ (((n0 + 1) & 7) << 3))] = f2b(w.y);
        sWT[(n0 + 2) * 128 + (k ^ (((n0 + 2) & 7) << 3))] = f2b(w.z);
        sWT[(n0 + 3) * 128 + (k ^ (((n0 + 3) & 7) << 3))] = f2b(w.w);
    }
    if (tid < 256) red[tid] = 0.f;
    __syncthreads();

    const int lane = tid & 63;
    const int wave = tid >> 6;
    const int r0   = blockIdx.x * 256 + wave * 16;
    const int rl   = lane & 15;
    const int kg   = lane >> 4;
    int rr = r0 + rl;
    int rclamp = rr < N ? rr : N - 1;
    const unsigned short* arow = A + (size_t)rclamp * DIM + kg * 8;

    f32x4 acc[8];
    #pragma unroll
    for (int nt = 0; nt < 8; ++nt) acc[nt] = (f32x4)(0.f);

    #pragma unroll
    for (int kk = 0; kk < 128; kk += 32) {
        bf16x8 a8 = *(const bf16x8*)(arow + kk);
        if (APPLY_BN) {
            const int cb = kk + kg * 8;
            bf16x8 tt;
            #pragma unroll
            for (int j = 0; j < 8; ++j) {
                float f = b2f((unsigned short)a8[j]) * sss[cb + j] + sss[128 + cb + j];
                tt[j] = (short)f2b(fmaxf(f, 0.f));
            }
            a8 = tt;
        }
        const int ks = kk + kg * 8;
        #pragma unroll
        for (int nt = 0; nt < 8; ++nt) {
            int n = nt * 16 + rl;
            bf16x8 b8 = *(const bf16x8*)&sWT[n * 128 + (ks ^ ((n & 7) << 3))];
            acc[nt] = __builtin_amdgcn_mfma_f32_16x16x32_bf16(a8, b8, acc[nt], 0, 0, 0);
        }
    }

    const int orow0 = r0 + kg * 4;
    #pragma unroll
    for (int nt = 0; nt < 8; ++nt) {
        int n = nt * 16 + rl;
        float bb = bias[n];
        float ls = 0.f, ls2 = 0.f;
        #pragma unroll
        for (int j = 0; j < 4; ++j) {
            int r = orow0 + j;
            if (r < N) {
                float v = acc[nt][j] + bb;
                if (OUT_BF16) ((unsigned short*)outp)[(size_t)r * DIM + n] = f2b(v);
                else          ((float*)outp)[(size_t)r * DIM + n] = v;
                ls += v; ls2 += v * v;
            }
        }
        ls  += __shfl_xor(ls, 16);  ls  += __shfl_xor(ls, 32);
        ls2 += __shfl_xor(ls2, 16); ls2 += __shfl_xor(ls2, 32);
        if (kg == 0) { atomicAdd(&red[n], ls); atomicAdd(&red[128 + n], ls2); }
    }
    __syncthreads();
    if (tid < 256) atomicAdd(&stats[tid], red[tid]);
}

// ---------------------------------------------------------------- final BN+ReLU: bf16 h2 -> fp32 out, BN finalized in-block
__global__ __launch_bounds__(256)
void bn_relu_out_b(const unsigned short* __restrict__ h2b,
                   const float* __restrict__ stats, const float* __restrict__ gamma,
                   const float* __restrict__ beta, float invN,
                   float* __restrict__ out, int n8)
{
    __shared__ float sss[256];
    const int tid = threadIdx.x;
    if (tid < 128) {
        float mu  = stats[tid] * invN;
        float var = fmaxf(stats[128 + tid] * invN - mu * mu, 0.f);
        float sc  = gamma[tid] * rsqrtf(var + 1e-5f);
        sss[tid]       = sc;
        sss[128 + tid] = beta[tid] - mu * sc;
    }
    __syncthreads();
    int i = blockIdx.x * 256 + tid;
    if (i >= n8) return;
    int c = (i * 8) & 127;
    bf16x8 v = *(const bf16x8*)(h2b + (size_t)i * 8);
    float4 o0, o1;
    o0.x = fmaxf(b2f((unsigned short)v[0]) * sss[c+0] + sss[128+c+0], 0.f);
    o0.y = fmaxf(b2f((unsigned short)v[1]) * sss[c+1] + sss[128+c+1], 0.f);
    o0.z = fmaxf(b2f((unsigned short)v[2]) * sss[c+2] + sss[128+c+2], 0.f);
    o0.w = fmaxf(b2f((unsigned short)v[3]) * sss[c+3] + sss[128+c+3], 0.f);
    o1.x = fmaxf(b2f((unsigned short)v[4]) * sss[c+4] + sss[128+c+4], 0.f);
    o1.y = fmaxf(b2f((unsigned short)v[5]) * sss[c+5] + sss[128+c+5], 0.f);
    o1.z = fmaxf(b2f((unsigned short)v[6]) * sss[c+6] + sss[128+c+6], 0.f);
    o1.w = fmaxf(b2f((unsigned short)v[7]) * sss[c+7] + sss[128+c+7], 0.f);
    ((float4*)out)[i * 2 + 0] = o0;
    ((float4*)out)[i * 2 + 1] = o1;
}

// ----------------------------------------------------------------
extern "C" void kernel_launch(void* const* d_in, const int* in_sizes, int n_in,
                              void* d_out, int out_size, void* d_ws, size_t ws_size,
                              hipStream_t stream) {
    const float* x    = (const float*)d_in[0];
    const int*   ei   = (const int*)  d_in[1];
    const float* W1   = (const float*)d_in[2];
    const float* b1   = (const float*)d_in[3];
    const float* g1   = (const float*)d_in[4];
    const float* be1  = (const float*)d_in[5];
    const float* W2   = (const float*)d_in[6];
    const float* b2   = (const float*)d_in[7];
    const float* g2   = (const float*)d_in[8];
    const float* be2  = (const float*)d_in[9];
    const float* epsp = (const float*)d_in[10];
    float* out = (float*)d_out;

    const int N = in_sizes[0] / DIM;   // 100000
    const int E = in_sizes[1] / 2;     // 1600000
    const int* src = ei;
    const int* dst = ei + E;
    const int nbins = (N + BINSZ - 1) >> BINSHIFT;   // 782

    // workspace layout (~76.8 MB + tail) — identical to R9:
    //   [0]     xb  [N*128 ushort]  25.6 MB
    //   [SZ]    h1b [N*128 ushort]  25.6 MB
    //   [2SZ]   binned [nbins*BCAP u32] 8 MB (dead after agg_gemm1) -> h2b overlays
    //   [3SZ]   tail: gcur[1024 u32] | stats1[256 f] | stats2[256 f]
    const size_t SZ = (size_t)N * DIM * sizeof(unsigned short);
    char* w = (char*)d_ws;
    unsigned short* xb  = (unsigned short*)w;
    unsigned short* h1b = (unsigned short*)(w + SZ);
    unsigned* binned    = (unsigned*)(w + 2 * SZ);
    unsigned short* h2b = (unsigned short*)(w + 2 * SZ);
    unsigned* gcur      = (unsigned*)(w + 3 * SZ);
    float* stats1 = (float*)(gcur + 1024);
    float* stats2 = stats1 + 256;

    const float invN = 1.0f / (float)N;
    const int n8 = N * DIM / 8;
    const int ebB = (E + EPB - 1) / EPB;            // 196 binning blocks
    const int castB = (n8 + 1023) / 1024;           // 1563 cast blocks

    // 1: zero gcur+stats1+stats2 (contiguous)
    hipMemsetAsync(gcur, 0, (1024 + 512) * sizeof(unsigned), stream);
    // 2: bin edges (first 196 blocks) + cast x->bf16 (rest), overlapped
    prep<<<ebB + castB, 1024, 0, stream>>>(src, dst, gcur, binned, E, nbins, x, xb, n8, ebB);
    // 3: per-bin sort(LDS) + gather -> swizzled LDS A + GEMM1 + stats1
    agg_gemm1<<<nbins, 512, 0, stream>>>(xb, epsp, gcur, binned, W1, b1, h1b, stats1, N);
    // 4: layer 2 GEMM (BN1+ReLU fused on input, finalized in-block) + stats2
    const int gblocks = (N + 255) / 256;
    gemm_mfma<true, true><<<gblocks, 1024, 0, stream>>>(
        h1b, W2, b2, stats1, g1, be1, invN, h2b, stats2, N);
    // 5: BN2+ReLU finalized in-block -> fp32 out
    bn_relu_out_b<<<(n8 + 255) / 256, 256, 0, stream>>>(h2b, stats2, g2, be2, invN, out, n8);
}